// Round 4
// 966.548 us; speedup vs baseline: 1.0246x; 1.0246x over previous
//
#include <hip/hip_runtime.h>

#define NTOK 8192
#define DIN 1024
#define DH   4096
#define DOUT 1024
#define NE   8
#define MAXTILES 136              // ceil-padded: 16384/128 + 8
#define SLOTCAP  (MAXTILES*128)   // 17408

typedef __bf16 bf16x8 __attribute__((ext_vector_type(8)));
typedef float  f32x4  __attribute__((ext_vector_type(4)));

// ---- workspace layout (bytes) ----
constexpr size_t OFF_W1T  = 0;                       // 8*1024*4096*2 = 67108864
constexpr size_t OFF_W2T  = 67108864;                // 67108864
constexpr size_t OFF_XB   = 134217728;               // 8192*1024*2 = 16777216
constexpr size_t OFF_H    = 150994944;               // 17408*4096*2 = 142606336
constexpr size_t OFF_SROW = 293601280;               // 17408*4
constexpr size_t OFF_SW   = 293670912;               // 17408*4
constexpr size_t OFF_TIDX = 293740544;               // 8192*2*4
constexpr size_t OFF_TW   = 293806080;               // 8192*2*4
constexpr size_t OFF_CTRL = 293871616;               // count[8] @0, fill[8] @32, tile_off[9] @64 (128 B)
constexpr size_t OFF_PART = 293871744;               // 2048*8*4 = 65536

__device__ __forceinline__ ushort f2bf(float f){
  unsigned u = __float_as_uint(f);
  u += 0x7fff + ((u >> 16) & 1);          // RNE
  return (ushort)(u >> 16);
}

#define GLDS(g,l) __builtin_amdgcn_global_load_lds( \
    (const __attribute__((address_space(1))) void*)(g), \
    (__attribute__((address_space(3))) void*)(l), 16, 0, 0)

// ---------------- x -> bf16 ----------------
__global__ void k_cvt_x(const float4* __restrict__ x, ushort4* __restrict__ xb){
  int i = blockIdx.x * 256 + threadIdx.x;   // i-th float4
  float4 v = x[i];
  ushort4 o;
  o.x = f2bf(v.x); o.y = f2bf(v.y); o.z = f2bf(v.z); o.w = f2bf(v.w);
  xb[i] = o;
}

// ------------- W[E][R][C] f32 -> WT[E][C][R] bf16 -------------
__global__ void k_transpose(const float* __restrict__ W, ushort* __restrict__ WT, int R, int C){
  __shared__ ushort tl[64][65];
  int e  = blockIdx.z;
  int r0 = blockIdx.x * 64, c0 = blockIdx.y * 64;
  const float* Wp  = W  + (size_t)e * R * C;
  ushort*      WTp = WT + (size_t)e * R * C;
  int tr = threadIdx.x >> 6, tc = threadIdx.x & 63;
#pragma unroll
  for (int i = 0; i < 16; i++){
    int r = tr + i * 4;
    tl[r][tc] = f2bf(Wp[(size_t)(r0 + r) * C + c0 + tc]);
  }
  __syncthreads();
#pragma unroll
  for (int i = 0; i < 16; i++){
    int r = tr + i * 4;
    WTp[(size_t)(c0 + r) * R + r0 + tc] = tl[tc][r];
  }
}

// ---------------- gate: logits, softmax, top-2, counts ----------------
__global__ void k_gate(const float* __restrict__ x, const float* __restrict__ gw,
                       const float* __restrict__ gb, float* __restrict__ probs_out,
                       int* __restrict__ topk_idx, float* __restrict__ topk_w,
                       int* __restrict__ count, float* __restrict__ partial){
  __shared__ float psum[8];
  __shared__ int   pcnt[8];
  int wv = threadIdx.x >> 6, lane = threadIdx.x & 63;
  int row = blockIdx.x * 4 + wv;
  if (threadIdx.x < 8){ psum[threadIdx.x] = 0.f; pcnt[threadIdx.x] = 0; }
  __syncthreads();

  const float4* x4 = (const float4*)(x + (size_t)row * DIN);
  float acc[8];
#pragma unroll
  for (int e = 0; e < 8; e++) acc[e] = 0.f;
#pragma unroll
  for (int j = 0; j < 4; j++){
    float4 v = x4[j * 64 + lane];
    int kbase = (j * 64 + lane) * 4;
#pragma unroll
    for (int c = 0; c < 4; c++){
      float xv = (&v.x)[c];
      const float4* g4 = (const float4*)(gw + (size_t)(kbase + c) * 8);
      float4 g0 = g4[0], g1 = g4[1];
      acc[0] += xv * g0.x; acc[1] += xv * g0.y; acc[2] += xv * g0.z; acc[3] += xv * g0.w;
      acc[4] += xv * g1.x; acc[5] += xv * g1.y; acc[6] += xv * g1.z; acc[7] += xv * g1.w;
    }
  }
#pragma unroll
  for (int e = 0; e < 8; e++)
#pragma unroll
    for (int off = 32; off; off >>= 1) acc[e] += __shfl_xor(acc[e], off, 64);

  float lg[8], p[8], mx = -1e30f, s = 0.f;
#pragma unroll
  for (int e = 0; e < 8; e++){ lg[e] = acc[e] + gb[e]; mx = fmaxf(mx, lg[e]); }
#pragma unroll
  for (int e = 0; e < 8; e++){ p[e] = expf(lg[e] - mx); s += p[e]; }
  float inv = 1.f / s;
#pragma unroll
  for (int e = 0; e < 8; e++) p[e] *= inv;

  if (lane < 8) probs_out[(size_t)row * 8 + lane] = p[lane];

  if (lane == 0){
    int i1 = 0; float v1 = p[0];
#pragma unroll
    for (int e = 1; e < 8; e++) if (p[e] > v1){ v1 = p[e]; i1 = e; }
    int i2 = -1; float v2 = -1.f;
#pragma unroll
    for (int e = 0; e < 8; e++){ if (e == i1) continue; if (p[e] > v2){ v2 = p[e]; i2 = e; } }
    float denom = 1.f / (v1 + v2 + 1e-10f);
    topk_idx[row * 2]     = i1;  topk_idx[row * 2 + 1] = i2;
    topk_w  [row * 2]     = v1 * denom;  topk_w[row * 2 + 1] = v2 * denom;
    atomicAdd(&pcnt[i1], 1); atomicAdd(&pcnt[i2], 1);
  }
  if (lane < 8) atomicAdd(&psum[lane], p[lane]);
  __syncthreads();
  if (threadIdx.x < 8){
    partial[(size_t)blockIdx.x * 8 + threadIdx.x] = psum[threadIdx.x];
    if (pcnt[threadIdx.x]) atomicAdd(&count[threadIdx.x], pcnt[threadIdx.x]);
  }
}

// ---------------- aux loss + tile offsets ----------------
__global__ void k_aux(const float* __restrict__ partial, const int* __restrict__ count,
                      float* __restrict__ aux_out, int* __restrict__ tile_off){
  __shared__ float red[256];
  __shared__ float tot[8];
  int t = threadIdx.x, e = t & 7;
  float s = 0.f;
  for (int b = (t >> 3); b < 2048; b += 32) s += partial[(size_t)b * 8 + e];
  red[t] = s; __syncthreads();
  if (t < 8){ float v = 0.f; for (int c = 0; c < 32; c++) v += red[c * 8 + t]; tot[t] = v; }
  __syncthreads();
  if (t == 0){
    float aux = 0.f;
    for (int i = 0; i < 8; i++){
      float m = tot[i] * (1.f / 8192.f);
      aux += m * logf(m * 8.f + 1e-10f);
    }
    aux_out[0] = aux;
    int off = 0;
    for (int i = 0; i < 8; i++){ tile_off[i] = off; off += (count[i] + 127) >> 7; }
    tile_off[8] = off;
  }
}

// ---------------- scatter assignments into padded slots ----------------
__global__ void k_scatter(const int* __restrict__ topk_idx, const float* __restrict__ topk_w,
                          const int* __restrict__ tile_off, int* __restrict__ fill,
                          int* __restrict__ slot_row, float* __restrict__ slot_w){
  int i = blockIdx.x * 256 + threadIdx.x;   // assignment 0..16383
  int row = i >> 1;
  int e = topk_idx[i];
  float w = topk_w[i];
  int lane = threadIdx.x & 63;
  int pos = 0;
#pragma unroll
  for (int ex = 0; ex < 8; ex++){
    unsigned long long mask = __ballot(e == ex);
    if (e == ex){
      int leader = __ffsll((long long)mask) - 1;
      int base = 0;
      if (lane == leader) base = atomicAdd(&fill[ex], (int)__popcll(mask));
      base = __shfl(base, leader, 64);
      pos = base + (int)__popcll(mask & ((1ull << lane) - 1ull));
    }
  }
  int slot = tile_off[e] * 128 + pos;
  slot_row[slot] = row;
  slot_w[slot]   = w;
}

// ---------------- GEMM1: H = relu(X_gathered @ w1t^T + b1), bf16 out ----------------
__global__ __launch_bounds__(256) void k_gemm1(
    const ushort* __restrict__ xb, const ushort* __restrict__ w1t,
    const float* __restrict__ b1, const int* __restrict__ slot_row,
    const int* __restrict__ tile_off, ushort* __restrict__ H){
  __shared__ ushort As[128 * 32];
  __shared__ ushort Bs[128 * 32];
  // T1: bijective XCD swizzle over the linearized 2-D grid (136*32 = 4352, %8==0).
  // tileN-fastest within each XCD chunk -> A-tile (256 KB) stays L2-hot per N-sweep.
  {
  }
  int lin = blockIdx.y * gridDim.x + blockIdx.x;      // 0..4351
  int wg  = (lin & 7) * (MAXTILES * (DH / 128) / 8) + (lin >> 3);
  int tileM = wg >> 5, tileN = wg & 31;               // NTN = DH/128 = 32
  if (tileM >= tile_off[8]) return;
  int e = 0;
  while (e < 7 && tile_off[e + 1] <= tileM) e++;
  int m0 = tileM * 128, n0 = tileN * 128;
  int t = threadIdx.x;

  const ushort* aBase[2]; const ushort* bBase[2];
#pragma unroll
  for (int i = 0; i < 2; i++){
    int c = i * 256 + t, r = c >> 2, cc = c & 3;
    aBase[i] = xb  + (size_t)slot_row[m0 + r] * DIN + cc * 8;
    bBase[i] = w1t + ((size_t)e * DH + n0 + r) * DIN + cc * 8;
  }
  int wv = t >> 6, lane = t & 63;
  int wm = wv >> 1, wn = wv & 1, quad = lane >> 4, lc = lane & 15;
  f32x4 acc[4][4] = {};

  for (int k0 = 0; k0 < DIN; k0 += 32){
#pragma unroll
    for (int i = 0; i < 2; i++){
      int c = i * 256 + t;
      GLDS(aBase[i] + k0, As + c * 8);
      GLDS(bBase[i] + k0, Bs + c * 8);
    }
    __syncthreads();
    bf16x8 a[4], b[4];
#pragma unroll
    for (int i = 0; i < 4; i++) a[i] = *(const bf16x8*)(As + (wm * 64 + i * 16 + lc) * 32 + quad * 8);
#pragma unroll
    for (int j = 0; j < 4; j++) b[j] = *(const bf16x8*)(Bs + (wn * 64 + j * 16 + lc) * 32 + quad * 8);
#pragma unroll
    for (int i = 0; i < 4; i++)
#pragma unroll
      for (int j = 0; j < 4; j++)
        acc[i][j] = __builtin_amdgcn_mfma_f32_16x16x32_bf16(a[i], b[j], acc[i][j], 0, 0, 0);
    __syncthreads();
  }

  const float* b1e = b1 + (size_t)e * DH;
#pragma unroll
  for (int i = 0; i < 4; i++){
#pragma unroll
    for (int r = 0; r < 4; r++){
      int slot = m0 + wm * 64 + i * 16 + quad * 4 + r;
      ushort* hrow = H + (size_t)slot * DH;
#pragma unroll
      for (int j = 0; j < 4; j++){
        int col = n0 + wn * 64 + j * 16 + lc;
        float v = acc[i][j][r] + b1e[col];
        hrow[col] = f2bf(fmaxf(v, 0.f));
      }
    }
  }
}

// ---------------- GEMM2: out[row] += w * (H @ w2t^T + b2) ----------------
__global__ __launch_bounds__(256) void k_gemm2(
    const ushort* __restrict__ H, const ushort* __restrict__ w2t,
    const float* __restrict__ b2, const int* __restrict__ slot_row,
    const float* __restrict__ slot_w, const int* __restrict__ tile_off,
    float* __restrict__ out){
  __shared__ ushort As[128 * 32];
  __shared__ ushort Bs[128 * 32];
  // T1: bijective XCD swizzle (136*8 = 1088, %8==0), tileN-fastest per chunk.
  int lin = blockIdx.y * gridDim.x + blockIdx.x;      // 0..1087
  int wg  = (lin & 7) * (MAXTILES * (DOUT / 128) / 8) + (lin >> 3);
  int tileM = wg >> 3, tileN = wg & 7;                // NTN = DOUT/128 = 8
  if (tileM >= tile_off[8]) return;
  int e = 0;
  while (e < 7 && tile_off[e + 1] <= tileM) e++;
  int m0 = tileM * 128, n0 = tileN * 128;
  int t = threadIdx.x;

  const ushort* aBase[2]; const ushort* bBase[2];
#pragma unroll
  for (int i = 0; i < 2; i++){
    int c = i * 256 + t, r = c >> 2, cc = c & 3;
    aBase[i] = H   + (size_t)(m0 + r) * DH + cc * 8;
    bBase[i] = w2t + ((size_t)e * DOUT + n0 + r) * DH + cc * 8;
  }
  int wv = t >> 6, lane = t & 63;
  int wm = wv >> 1, wn = wv & 1, quad = lane >> 4, lc = lane & 15;
  f32x4 acc[4][4] = {};

  for (int k0 = 0; k0 < DH; k0 += 32){
#pragma unroll
    for (int i = 0; i < 2; i++){
      int c = i * 256 + t;
      GLDS(aBase[i] + k0, As + c * 8);
      GLDS(bBase[i] + k0, Bs + c * 8);
    }
    __syncthreads();
    bf16x8 a[4], b[4];
#pragma unroll
    for (int i = 0; i < 4; i++) a[i] = *(const bf16x8*)(As + (wm * 64 + i * 16 + lc) * 32 + quad * 8);
#pragma unroll
    for (int j = 0; j < 4; j++) b[j] = *(const bf16x8*)(Bs + (wn * 64 + j * 16 + lc) * 32 + quad * 8);
#pragma unroll
    for (int i = 0; i < 4; i++)
#pragma unroll
      for (int j = 0; j < 4; j++)
        acc[i][j] = __builtin_amdgcn_mfma_f32_16x16x32_bf16(a[i], b[j], acc[i][j], 0, 0, 0);
    __syncthreads();
  }

  const float* b2e = b2 + (size_t)e * DOUT;
#pragma unroll
  for (int i = 0; i < 4; i++){
#pragma unroll
    for (int r = 0; r < 4; r++){
      int slot = m0 + wm * 64 + i * 16 + quad * 4 + r;
      float w = slot_w[slot];
      if (w == 0.f) continue;
      float* orow = out + (size_t)slot_row[slot] * DOUT;
#pragma unroll
      for (int j = 0; j < 4; j++){
        int col = n0 + wn * 64 + j * 16 + lc;
        atomicAdd(orow + col, w * (acc[i][j][r] + b2e[col]));
      }
    }
  }
}

extern "C" void kernel_launch(void* const* d_in, const int* in_sizes, int n_in,
                              void* d_out, int out_size, void* d_ws, size_t ws_size,
                              hipStream_t stream){
  const float* x      = (const float*)d_in[0];
  const float* gate_w = (const float*)d_in[1];
  const float* gate_b = (const float*)d_in[2];
  const float* w1     = (const float*)d_in[3];
  const float* b1     = (const float*)d_in[4];
  const float* w2     = (const float*)d_in[5];
  const float* b2     = (const float*)d_in[6];
  float* out = (float*)d_out;

  char* ws = (char*)d_ws;
  ushort* W1T   = (ushort*)(ws + OFF_W1T);
  ushort* W2T   = (ushort*)(ws + OFF_W2T);
  ushort* XB    = (ushort*)(ws + OFF_XB);
  ushort* H     = (ushort*)(ws + OFF_H);
  int*    SROW  = (int*)   (ws + OFF_SROW);
  float*  SW    = (float*) (ws + OFF_SW);
  int*    TIDX  = (int*)   (ws + OFF_TIDX);
  float*  TW    = (float*) (ws + OFF_TW);
  int*    COUNT = (int*)   (ws + OFF_CTRL);
  int*    FILL  = (int*)   (ws + OFF_CTRL + 32);
  int*    TOFF  = (int*)   (ws + OFF_CTRL + 64);
  float*  PART  = (float*) (ws + OFF_PART);

  float* aux_out   = out + (size_t)NTOK * DOUT;       // 8388608
  float* probs_out = aux_out + 1;                      // 8388609

  hipMemsetAsync(d_out, 0, (size_t)out_size * 4, stream);
  hipMemsetAsync(ws + OFF_CTRL, 0, 128, stream);
  hipMemsetAsync(ws + OFF_SROW, 0, (size_t)SLOTCAP * 8, stream);  // slot_row + slot_w

  k_cvt_x<<<dim3((NTOK * DIN / 4) / 256), 256, 0, stream>>>((const float4*)x, (ushort4*)XB);
  k_transpose<<<dim3(DIN / 64, DH / 64, NE), 256, 0, stream>>>(w1, W1T, DIN, DH);
  k_transpose<<<dim3(DH / 64, DOUT / 64, NE), 256, 0, stream>>>(w2, W2T, DH, DOUT);
  k_gate<<<dim3(NTOK / 4), 256, 0, stream>>>(x, gate_w, gate_b, probs_out, TIDX, TW, COUNT, PART);
  k_aux<<<dim3(1), 256, 0, stream>>>(PART, COUNT, aux_out, TOFF);
  k_scatter<<<dim3(NTOK * 2 / 256), 256, 0, stream>>>(TIDX, TW, TOFF, FILL, SROW, SW);
  k_gemm1<<<dim3(MAXTILES, DH / 128), 256, 0, stream>>>(XB, W1T, b1, SROW, TOFF, H);
  k_gemm2<<<dim3(MAXTILES, DOUT / 128), 256, 0, stream>>>(H, W2T, b2, SROW, SW, TOFF, out);
}